// Round 11
// baseline (1011.373 us; speedup 1.0000x reference)
//
#include <hip/hip_runtime.h>
#include <cmath>

#define HH 128
#define WW 128
#define HWSZ (HH * WW)

typedef __attribute__((ext_vector_type(8))) short short8v;
typedef __attribute__((ext_vector_type(4))) float f32x4;

static __device__ __forceinline__ int imin(int a, int b) { return a < b ? a : b; }
static __device__ __forceinline__ int imax(int a, int b) { return a > b ? a : b; }

// Split fp32 -> bf16 hi + bf16 lo (RNE both), f ~= hi + lo with residual ~2^-17|f|
static __device__ __forceinline__ void bf16split(float f, short& hi, short& lo) {
  unsigned u = __float_as_uint(f);
  unsigned rh = u + 0x7fffu + ((u >> 16) & 1u);
  hi = (short)(rh >> 16);
  float fh = __uint_as_float((rh >> 16) << 16);
  float res = f - fh;
  unsigned v = __float_as_uint(res);
  unsigned rl = v + 0x7fffu + ((v >> 16) & 1u);
  lo = (short)(rl >> 16);
}

// ---------------------------------------------------------------------------
// NCHW fp32 -> NHWC fp32 (x for deform), channel-padded.
// ---------------------------------------------------------------------------
__global__ void nhwc_kernel(const float* __restrict__ src, float* __restrict__ dst,
                            int C_real, int CP) {
  const int npx = 4 * HWSZ;
  int idx = blockIdx.x * 256 + threadIdx.x;
  int total = (CP / 8) * npx;
  if (idx >= total) return;
  const int pixg = idx % npx;
  const int c8   = idx / npx;
  const int b    = pixg / HWSZ;
  const int pix  = pixg % HWSZ;
  float v[8];
#pragma unroll
  for (int j = 0; j < 8; ++j) {
    const int c = c8 * 8 + j;
    v[j] = (c < C_real) ? src[((size_t)b * C_real + c) * HWSZ + pix] : 0.f;
  }
  float* dp = dst + (size_t)pixg * CP + c8 * 8;
  *(float4*)dp       = make_float4(v[0], v[1], v[2], v[3]);
  *(float4*)(dp + 4) = make_float4(v[4], v[5], v[6], v[7]);
}

// ---------------------------------------------------------------------------
// NCHW fp32 -> NHWC bf16 hi/lo planes, channel-padded (pads = 0).
// ---------------------------------------------------------------------------
__global__ void split_nhwc_kernel(const float* __restrict__ src,
                                  short* __restrict__ dhi, short* __restrict__ dlo,
                                  int C_real, int CP) {
  const int npx = 4 * HWSZ;
  int idx = blockIdx.x * 256 + threadIdx.x;
  int total = (CP / 8) * npx;
  if (idx >= total) return;
  const int pixg = idx % npx;
  const int c8   = idx / npx;
  const int b    = pixg / HWSZ;
  const int pix  = pixg % HWSZ;
  short8v h, l;
#pragma unroll
  for (int j = 0; j < 8; ++j) {
    const int c = c8 * 8 + j;
    float v = (c < C_real) ? src[((size_t)b * C_real + c) * HWSZ + pix] : 0.f;
    short hh, ll;
    bf16split(v, hh, ll);
    h[j] = hh;
    l[j] = ll;
  }
  *(short8v*)(dhi + (size_t)pixg * CP + c8 * 8) = h;
  *(short8v*)(dlo + (size_t)pixg * CP + c8 * 8) = l;
}

// ---------------------------------------------------------------------------
// MFMA weight prepack: w[cout][cin_real][3][3] -> per-lane B-fragments.
// K order: ks = cinblk*9 + tap; within a K-step of 32: k = (lane>>4)*8 + j.
// ---------------------------------------------------------------------------
__global__ void wpack_kernel(const float* __restrict__ w, short* __restrict__ whi,
                             short* __restrict__ wlo, int nct, int nks,
                             int cin_real, int cout) {
  int idx = blockIdx.x * 256 + threadIdx.x;
  int total = nct * nks * 512;
  if (idx >= total) return;
  int j    = idx & 7;
  int lane = (idx >> 3) & 63;
  int t2   = idx >> 9;
  int ks   = t2 % nks;
  int ct   = t2 / nks;
  int cinb = ks / 9, tap = ks % 9;
  int cin = cinb * 32 + (lane >> 4) * 8 + j;
  int co  = ct * 16 + (lane & 15);
  float v = 0.f;
  if (co < cout && cin < cin_real) v = w[((size_t)co * cin_real + cin) * 9 + tap];
  short hi, lo;
  bf16split(v, hi, lo);
  whi[idx] = hi;
  wlo[idx] = lo;
}

// ---------------------------------------------------------------------------
// 3x3 conv via MFMA bf16 3-product split, LDS-free, barrier-free.
// Inputs are PRE-SPLIT NHWC bf16 hi/lo planes -> A-frag is 2 direct 16B loads,
// zero VALU split in the hot loop. Output: bf16 hi/lo planes (outf==null) or
// fp32 NHWC (outf!=null, for head). D: col=lane&15 (co), row=(lane>>4)*4+reg.
// ---------------------------------------------------------------------------
template <int NCT>
__global__ __launch_bounds__(256, 2) void conv_bf16_kernel(
    const short* __restrict__ inh, const short* __restrict__ inl,
    const short* __restrict__ wh, const short* __restrict__ wl,
    const float* __restrict__ bias, short* __restrict__ outh,
    short* __restrict__ outl, float* __restrict__ outf,
    int CP, int CB, int OP, int cout, int lrelu) {
  const int tid = threadIdx.x;
  int bid = blockIdx.x;                  // 1024 blocks, 1024%8==0
  bid = (bid & 7) * 128 + (bid >> 3);    // XCD-contiguous chunks of 128
  const int x0 = (bid & 1) * 64;
  const int y  = (bid >> 1) & 127;
  const int b  = bid >> 8;
  const int lane = tid & 63;
  const int wv = tid >> 6;
  const int m = lane & 15;
  const int g = lane >> 4;
  const int NKS = CB * 9;
  const int gx = x0 + wv * 16 + m;       // this lane's output pixel x

  const short8v kZero = {0, 0, 0, 0, 0, 0, 0, 0};

  f32x4 acc[NCT];
#pragma unroll
  for (int ct = 0; ct < NCT; ++ct) acc[ct] = (f32x4){0.f, 0.f, 0.f, 0.f};

  const short* ihb = inh + (size_t)b * HWSZ * CP;
  const short* ilb = inl + (size_t)b * HWSZ * CP;

  for (int cb = 0; cb < CB; ++cb) {
    const int cbase = cb * 32 + g * 8;
#pragma unroll
    for (int tap = 0; tap < 9; ++tap) {
      const int r = tap / 3;
      const int c = tap - r * 3;
      const int gy  = y + r - 1;
      const int gxx = gx + c - 1;
      const bool valid = ((unsigned)gy < (unsigned)HH) && ((unsigned)gxx < (unsigned)WW);
      const int cy = imin(imax(gy, 0), HH - 1);
      const int cx = imin(imax(gxx, 0), WW - 1);
      const size_t poff = (size_t)(cy * WW + cx) * CP + cbase;
      short8v ah = *(const short8v*)(ihb + poff);
      short8v al = *(const short8v*)(ilb + poff);
      if (!valid) {
        ah = kZero;
        al = kZero;
      }
      const int ks = cb * 9 + tap;
#pragma unroll
      for (int ct = 0; ct < NCT; ++ct) {
        const size_t off = ((size_t)(ct * NKS + ks) * 64 + lane) * 8;
        short8v bh = *(const short8v*)(wh + off);
        short8v bl = *(const short8v*)(wl + off);
        acc[ct] = __builtin_amdgcn_mfma_f32_16x16x32_bf16(ah, bh, acc[ct], 0, 0, 0);
        acc[ct] = __builtin_amdgcn_mfma_f32_16x16x32_bf16(ah, bl, acc[ct], 0, 0, 0);
        acc[ct] = __builtin_amdgcn_mfma_f32_16x16x32_bf16(al, bh, acc[ct], 0, 0, 0);
      }
    }
  }

  // ---- epilogue
  const int co_l = lane & 15;
  const int px0  = x0 + wv * 16 + (lane >> 4) * 4;
#pragma unroll
  for (int ct = 0; ct < NCT; ++ct) {
    const int co = ct * 16 + co_l;
    if (co < cout) {
      const float bv = bias[co];
#pragma unroll
      for (int q = 0; q < 4; ++q) {
        float v = acc[ct][q] + bv;
        if (lrelu) v = (v >= 0.f) ? v : 0.1f * v;
        const size_t pidx = (size_t)b * HWSZ + y * WW + px0 + q;
        if (outf) {
          outf[pidx * OP + co] = v;
        } else {
          short h, l;
          bf16split(v, h, l);
          outh[pidx * OP + co] = h;
          outl[pidx * OP + co] = l;
        }
      }
    }
  }
}

// ---------------------------------------------------------------------------
// Modulated deformable conv 3x3 via MFMA, LDS-free, NHWC fp32 x / fp32 head.
// Per lane: 9-tap bilinear params in registers; per K-step gather 4 corners x
// 8 contiguous cins (2 float4 each), combine, split, 8ct x 3 MFMA.
// Output written NCHW fp32 (reference layout).
// ---------------------------------------------------------------------------
__global__ __launch_bounds__(256, 2) void deform_nhwc_kernel(
    const float* __restrict__ xt, const float* __restrict__ headt,
    const float* __restrict__ flow, const short* __restrict__ wh,
    const short* __restrict__ wl, const float* __restrict__ bias,
    float* __restrict__ out) {
  const int tid = threadIdx.x;
  int bid = blockIdx.x;                  // 1024 blocks
  bid = (bid & 7) * 128 + (bid >> 3);    // XCD-contiguous
  const int x0 = (bid & 1) * 64;
  const int y  = (bid >> 1) & 127;
  const int b  = bid >> 8;
  const int lane = tid & 63;
  const int wv = tid >> 6;
  const int m = lane & 15;
  const int g = lane >> 4;
  const int gx = x0 + wv * 16 + m;       // this lane's pixel (A row = lane&15)

  // ---- per-tap bilinear params for pixel (y, gx); head NHWC(32) contiguous
  int   i00[9], i01[9], i10[9], i11[9];
  float w00[9], w01[9], w10[9], w11[9];
  {
    const size_t pix = (size_t)y * WW + gx;
    const float* hb = headt + ((size_t)b * HWSZ + pix) * 32;
    const float fly = flow[((size_t)b * 2 + 1) * HWSZ + pix];   // flow[:,1] -> dy
    const float flx = flow[((size_t)b * 2 + 0) * HWSZ + pix];   // flow[:,0] -> dx
#pragma unroll
    for (int k = 0; k < 9; ++k) {
      const float hy = hb[2 * k];
      const float hx = hb[2 * k + 1];
      const float hm = hb[18 + k];
      const float dy = 3.f * tanhf(hy) + fly;
      const float dx = 3.f * tanhf(hx) + flx;
      const float py  = (float)(y - 1 + (k / 3)) + dy;
      const float pxx = (float)(gx - 1 + (k % 3)) + dx;
      const float y0f = floorf(py), x0f = floorf(pxx);
      const float fy = py - y0f, fx = pxx - x0f;
      const int iy0 = (int)y0f, ix0 = (int)x0f;
      const int iy1 = iy0 + 1,  ix1 = ix0 + 1;
      const float mm = 1.f / (1.f + expf(-hm));   // sigmoid mask folded in
      const float vy0 = (iy0 >= 0 && iy0 < HH) ? mm : 0.f;
      const float vy1 = (iy1 >= 0 && iy1 < HH) ? mm : 0.f;
      const float vx0 = (ix0 >= 0 && ix0 < WW) ? 1.f : 0.f;
      const float vx1 = (ix1 >= 0 && ix1 < WW) ? 1.f : 0.f;
      w00[k] = (1.f - fy) * (1.f - fx) * vy0 * vx0;
      w01[k] = (1.f - fy) * fx * vy0 * vx1;
      w10[k] = fy * (1.f - fx) * vy1 * vx0;
      w11[k] = fy * fx * vy1 * vx1;
      const int cy0 = imin(imax(iy0, 0), HH - 1);
      const int cy1 = imin(imax(iy1, 0), HH - 1);
      const int cx0 = imin(imax(ix0, 0), WW - 1);
      const int cx1 = imin(imax(ix1, 0), WW - 1);
      i00[k] = cy0 * WW + cx0;
      i01[k] = cy0 * WW + cx1;
      i10[k] = cy1 * WW + cx0;
      i11[k] = cy1 * WW + cx1;
    }
  }

  f32x4 acc[8];
#pragma unroll
  for (int ct = 0; ct < 8; ++ct) acc[ct] = (f32x4){0.f, 0.f, 0.f, 0.f};

  const float* xb = xt + (size_t)b * HWSZ * 128;

  for (int cinb = 0; cinb < 4; ++cinb) {
    const int cbase = cinb * 32 + g * 8;
#pragma unroll
    for (int tap = 0; tap < 9; ++tap) {
      const float* p00 = xb + (size_t)i00[tap] * 128 + cbase;
      const float* p01 = xb + (size_t)i01[tap] * 128 + cbase;
      const float* p10 = xb + (size_t)i10[tap] * 128 + cbase;
      const float* p11 = xb + (size_t)i11[tap] * 128 + cbase;
      f32x4 c00a = *(const f32x4*)p00, c00b = *(const f32x4*)(p00 + 4);
      f32x4 c01a = *(const f32x4*)p01, c01b = *(const f32x4*)(p01 + 4);
      f32x4 c10a = *(const f32x4*)p10, c10b = *(const f32x4*)(p10 + 4);
      f32x4 c11a = *(const f32x4*)p11, c11b = *(const f32x4*)(p11 + 4);
      short8v ah, al;
#pragma unroll
      for (int j = 0; j < 4; ++j) {
        float s0 = w00[tap] * c00a[j] + w01[tap] * c01a[j] +
                   w10[tap] * c10a[j] + w11[tap] * c11a[j];
        float s1 = w00[tap] * c00b[j] + w01[tap] * c01b[j] +
                   w10[tap] * c10b[j] + w11[tap] * c11b[j];
        short h, l;
        bf16split(s0, h, l);
        ah[j] = h; al[j] = l;
        bf16split(s1, h, l);
        ah[j + 4] = h; al[j + 4] = l;
      }
      const int ks = cinb * 9 + tap;
#pragma unroll
      for (int ct = 0; ct < 8; ++ct) {
        const size_t off = ((size_t)(ct * 36 + ks) * 64 + lane) * 8;
        short8v bh = *(const short8v*)(wh + off);
        short8v bl = *(const short8v*)(wl + off);
        acc[ct] = __builtin_amdgcn_mfma_f32_16x16x32_bf16(ah, bh, acc[ct], 0, 0, 0);
        acc[ct] = __builtin_amdgcn_mfma_f32_16x16x32_bf16(ah, bl, acc[ct], 0, 0, 0);
        acc[ct] = __builtin_amdgcn_mfma_f32_16x16x32_bf16(al, bh, acc[ct], 0, 0, 0);
      }
    }
  }

  // ---- epilogue: NCHW out. col = lane&15 (co), rows = (lane>>4)*4 + reg (px)
  const int co_l = lane & 15;
  const int pxw  = x0 + wv * 16 + (lane >> 4) * 4;
#pragma unroll
  for (int ct = 0; ct < 8; ++ct) {
    const int co = ct * 16 + co_l;
    const float bv = bias[co];
    float* op = out + ((size_t)(b * 128 + co) * HH + y) * WW + pxw;
    *(float4*)op = make_float4(acc[ct][0] + bv, acc[ct][1] + bv,
                               acc[ct][2] + bv, acc[ct][3] + bv);
  }
}

// ---------------------------------------------------------------------------
// Launch
// ---------------------------------------------------------------------------
extern "C" void kernel_launch(void* const* d_in, const int* in_sizes, int n_in,
                              void* d_out, int out_size, void* d_ws, size_t ws_size,
                              hipStream_t stream) {
  const float* x    = (const float*)d_in[0];
  const float* cond = (const float*)d_in[1];
  const float* flow = (const float*)d_in[2];
  const float* w1 = (const float*)d_in[3];
  const float* b1 = (const float*)d_in[4];
  const float* w2 = (const float*)d_in[5];
  const float* b2 = (const float*)d_in[6];
  const float* w3 = (const float*)d_in[7];
  const float* b3 = (const float*)d_in[8];
  const float* w4 = (const float*)d_in[9];
  const float* b4 = (const float*)d_in[10];
  const float* wd = (const float*)d_in[11];
  const float* bd = (const float*)d_in[12];
  float* out = (float*)d_out;
  float* ws  = (float*)d_ws;

  // workspace (float units), lifetime-aliased. Total 28,073,984 f = 112.3 MB
  // A region [0 .. 18,874,368):
  //   condt hi/lo [65536][288] bf16   (dead after conv1)
  //   then: f2 hi/lo  = [0 .. 8,388,608)        (conv2 out, conv3 in)
  //         xt fp32   = [8,388,608 .. 16,777,216) (written after conv1)
  //         headt f32 = [16,777,216 .. 18,874,368) (conv4 out, 32-pad NHWC)
  short* condth = (short*)ws;               // 18,874,368 shorts
  short* condtl = condth + 18874368;        // 18,874,368 shorts
  short* f2h    = (short*)ws;               // 8,388,608 shorts
  short* f2l    = f2h + 8388608;
  float* xt     = ws + 8388608;             // 8,388,608 f
  float* headt  = ws + 16777216;            // 2,097,152 f
  short* f1h    = (short*)(ws + 18874368);  // 8,388,608 shorts
  short* f1l    = f1h + 8388608;            // region ends at f 27,262,976
  short* pk1h = (short*)(ws + 27262976);    // 331,776 shorts
  short* pk1l = pk1h + 331776;
  short* pk2h = pk1l + 331776;              // 147,456 shorts
  short* pk2l = pk2h + 147456;
  short* pk3h = pk2l + 147456;
  short* pk3l = pk3h + 147456;
  short* pk4h = pk3l + 147456;              // 36,864 shorts
  short* pk4l = pk4h + 36864;
  short* pkdh = pk4l + 36864;               // 147,456 shorts
  short* pkdl = pkdh + 147456;

  dim3 blk256(256);

  // ---- transforms + weight prepacks
  hipLaunchKernelGGL(split_nhwc_kernel, dim3(9216), blk256, 0, stream, cond, condth, condtl, 261, 288);
  hipLaunchKernelGGL(wpack_kernel, dim3(1296), blk256, 0, stream, w1, pk1h, pk1l, 8, 81, 261, 128);
  hipLaunchKernelGGL(wpack_kernel, dim3(576),  blk256, 0, stream, w2, pk2h, pk2l, 8, 36, 128, 128);
  hipLaunchKernelGGL(wpack_kernel, dim3(576),  blk256, 0, stream, w3, pk3h, pk3l, 8, 36, 128, 128);
  hipLaunchKernelGGL(wpack_kernel, dim3(144),  blk256, 0, stream, w4, pk4h, pk4l, 2, 36, 128, 27);
  hipLaunchKernelGGL(wpack_kernel, dim3(576),  blk256, 0, stream, wd, pkdh, pkdl, 8, 36, 128, 128);

  dim3 cgrid(1024);   // 2 x-halves * 128 y * 4 b, XCD-swizzled in-kernel
  // conv1: condt(288, CB=9) -> f1 planes, lrelu
  hipLaunchKernelGGL(conv_bf16_kernel<8>, cgrid, blk256, 0, stream, condth, condtl,
                     pk1h, pk1l, b1, f1h, f1l, (float*)nullptr, 288, 9, 128, 128, 1);
  // x transform (after conv1: xt region overlapped condt)
  hipLaunchKernelGGL(nhwc_kernel, dim3(4096), blk256, 0, stream, x, xt, 128, 128);
  // conv2: f1 -> f2 planes, lrelu
  hipLaunchKernelGGL(conv_bf16_kernel<8>, cgrid, blk256, 0, stream, f1h, f1l,
                     pk2h, pk2l, b2, f2h, f2l, (float*)nullptr, 128, 4, 128, 128, 1);
  // conv3: f2 -> f1 planes, lrelu
  hipLaunchKernelGGL(conv_bf16_kernel<8>, cgrid, blk256, 0, stream, f2h, f2l,
                     pk3h, pk3l, b3, f1h, f1l, (float*)nullptr, 128, 4, 128, 128, 1);
  // conv4 (head): f1 -> headt fp32 NHWC(32), no activation
  hipLaunchKernelGGL(conv_bf16_kernel<2>, cgrid, blk256, 0, stream, f1h, f1l,
                     pk4h, pk4l, b4, (short*)nullptr, (short*)nullptr, headt, 128, 4, 32, 27, 0);
  // deformable conv via MFMA, NHWC gathers, NCHW output
  hipLaunchKernelGGL(deform_nhwc_kernel, cgrid, blk256, 0, stream, xt, headt, flow, pkdh, pkdl, bd, out);
}